// Round 10
// baseline (3309.513 us; speedup 1.0000x reference)
//
#include <hip/hip_runtime.h>
#include <stdint.h>

// IndexFlatIP top-k: sims = Q[512,512] @ X[262144,512]^T, per-row top-10
// indices (desc, ties -> lower index). Output int32 [512,10].
//
// Round 10 = round-7 all-glds pipeline with COALESCED B staging:
//  qprep      : Q fp32 -> f16 RTZ granules (A-tile order), 512 KB.
//  xprep_tiled: X fp32 -> f16 RTZ granules in B-TILE order (268 MB in d_ws):
//               tile (chunk,nt,kt) = 512 granules; granule g = koct*128+col
//               holds Xh[col][kt*32+koct*8 ..+8]. p1's B-glds reads are 1KB-
//               contiguous (r7's fatal 1KB-lane-stride is gone).
//  p1         : BM=128 BN=128 BK=32, 4 waves (64x64 wave tile), 4-deep LDS
//               bufs for A and B, pure global_load_lds staging (no reg
//               staging -> no spills, r8/r9 lesson), counted vmcnt(8) + raw
//               s_barrier (3-step latency slack). Fused per-row top-6 per
//               1024-col chunk. p2: pivot filter + exact fp32 rescore.
#define B_Q   512
#define N_IDX 262144
#define D_DIM 512
#define TOPK  10
#define CAND  6

constexpr int CHUNKS = 256;          // candidate chunks (1024 cols each)
constexpr int NR = N_IDX / CHUNKS;   // 1024
constexpr int BM = 128, BN = 128, BK = 32;
constexpr int NT = NR / BN;          // 8
constexpr int KT = D_DIM / BK;       // 16
constexpr int ITERS = NT * KT;       // 128
constexpr int NCAND = CHUNKS * CAND; // 1536
constexpr int CS_STRIDE = 17;

typedef _Float16 half8 __attribute__((ext_vector_type(8)));
typedef float    f32x4 __attribute__((ext_vector_type(4)));

__device__ __forceinline__ unsigned int pk16(float a, float b)
{
    return __builtin_bit_cast(unsigned int, __builtin_amdgcn_cvt_pkrtz(a, b));
}

__device__ __forceinline__ void glds16(const void* g, char* lds)
{
    __builtin_amdgcn_global_load_lds(
        (const __attribute__((address_space(1))) void*)g,
        (__attribute__((address_space(3))) void*)lds, 16, 0, 0);
}

// ------------------------------------------------------------------ qprep --
// A-tile granule order: tile (qt 0..3, kt 0..15), granule = koct*128 + row.
__global__ __launch_bounds__(256)
void qprep(const float* __restrict__ Q, uint4* __restrict__ Qsw4)
{
    const int n = blockIdx.x * 256 + threadIdx.x;   // 32768 granules
    const float4 p0 = reinterpret_cast<const float4*>(Q)[n * 2];
    const float4 p1 = reinterpret_cast<const float4*>(Q)[n * 2 + 1];
    uint4 u;
    u.x = pk16(p0.x, p0.y);
    u.y = pk16(p0.z, p0.w);
    u.z = pk16(p1.x, p1.y);
    u.w = pk16(p1.z, p1.w);
    const int rowg = n >> 6, oct = n & 63;
    const int kt = oct >> 2, koct = oct & 3;
    const int qt = rowg >> 7, row = rowg & 127;
    Qsw4[(qt * 16 + kt) * 512 + koct * 128 + row] = u;
}

// ------------------------------------------------------------ xprep_tiled --
// One block per (chunk, nt) panel of 128 X-rows. For each kt, each thread
// emits 2 granules: g = koct*128+col <- X[panel+col][kt*32+koct*8 ..+8].
// Reads: 32B/thread, koct-groups share 128B lines (L1/L2 absorbs).
// Writes: consecutive threads -> consecutive 16B, perfectly coalesced.
__global__ __launch_bounds__(256)
void xprep_tiled(const float* __restrict__ X, uint4* __restrict__ Xt4)
{
    const int chunk = blockIdx.x >> 3, nt = blockIdx.x & 7;
    const int t = threadIdx.x;
    const size_t rowbase = (size_t)(chunk * NR + nt * BN);
    for (int kt = 0; kt < 16; ++kt) {
        uint4* dst = Xt4 + ((size_t)(chunk * 8 + nt) * 16 + kt) * 512;
#pragma unroll
        for (int i = 0; i < 2; ++i) {
            const int g = t + i * 256;            // 0..511
            const int koct = g >> 7, col = g & 127;
            const float* src = X + (rowbase + col) * D_DIM + kt * 32 + koct * 8;
            const float4 p0 = *reinterpret_cast<const float4*>(src);
            const float4 p1 = *reinterpret_cast<const float4*>(src + 4);
            uint4 u;
            u.x = pk16(p0.x, p0.y);
            u.y = pk16(p0.z, p0.w);
            u.z = pk16(p1.x, p1.y);
            u.w = pk16(p1.z, p1.w);
            dst[g] = u;
        }
    }
}

// --------------------------------------------------------------------- p1 --
// Grid 1024 (qt = bx&3 fast -> 4 siblings share Xt tiles via L2/L3,
// chunk = bx>>2), block 256 = 4 waves (2M x 2N), wave tile 64x64.
// LDS 74240: Abuf[4] 8K @0, Bbuf[4] 8K @32768, Cs 128x17 f32 @65536.
// Per step per wave: 2 A-glds + 2 B-glds (all 1KB-contiguous), 8 ds_read_b128,
// 16 MFMA. 4-deep bufs; vmcnt(8) keeps 2 future steps in flight.
__global__ __launch_bounds__(256)
void faiss_p1(const uint4* __restrict__ Qsw4, const uint4* __restrict__ Xt4,
              float* __restrict__ cand_v, int* __restrict__ cand_i)
{
    __shared__ __align__(16) char smem[74240];
    float* Cs = (float*)(smem + 65536);

    const int tid  = threadIdx.x;
    const int lane = tid & 63;
    const int w    = tid >> 6;      // 0..3
    const int wm   = w >> 1;        // M half
    const int wn   = w & 1;         // N half
    const int qt    = blockIdx.x & 3;
    const int chunk = blockIdx.x >> 2;

    // A: wave w stages granules w*128 + {0..63, 64..127} of tile (qt, kt)
    const uint4* aTile = Qsw4 + qt * (16 * 512) + w * 128 + lane;
    // B: same granule pattern from the (chunk, nt, kt) tile; tile index
    // advances exactly with step s: offset = s*512.
    const uint4* bTile = Xt4 + (size_t)(chunk * 128) * 512 + w * 128 + lane;
    const int dDst = (w * 128) * 16;               // wave-uniform LDS bytes

    int a_off[4], b_off[4];
#pragma unroll
    for (int i = 0; i < 4; ++i) {
        a_off[i] = ((lane >> 4) * 128 + wm * 64 + i * 16 + (lane & 15)) * 16;
        b_off[i] = ((lane >> 4) * 128 + wn * 64 + i * 16 + (lane & 15)) * 16;
    }

    float topv[CAND]; int topi[CAND];
#pragma unroll
    for (int j = 0; j < CAND; ++j) { topv[j] = -3.0e38f; topi[j] = 0; }

    f32x4 acc[4][4];
#pragma unroll
    for (int mi = 0; mi < 4; ++mi)
#pragma unroll
        for (int ni = 0; ni < 4; ++ni) acc[mi][ni] = (f32x4)0.0f;

    auto issue = [&](int s, int buf) {
        const uint4* as = aTile + (s & 15) * 512;
        const uint4* bs = bTile + (size_t)s * 512;
        char* ab = smem + buf * 8192;
        char* bb = smem + 32768 + buf * 8192;
        glds16(as,      ab + dDst);
        glds16(as + 64, ab + dDst + 1024);
        glds16(bs,      bb + dDst);
        glds16(bs + 64, bb + dDst + 1024);
    };
    auto compute = [&](int buf) {
        const char* ab = smem + buf * 8192;
        const char* bb = smem + 32768 + buf * 8192;
        half8 af[4], bf[4];
#pragma unroll
        for (int mi = 0; mi < 4; ++mi)
            af[mi] = *reinterpret_cast<const half8*>(ab + a_off[mi]);
#pragma unroll
        for (int ni = 0; ni < 4; ++ni)
            bf[ni] = *reinterpret_cast<const half8*>(bb + b_off[ni]);
#pragma unroll
        for (int mi = 0; mi < 4; ++mi)
#pragma unroll
            for (int ni = 0; ni < 4; ++ni)
                acc[mi][ni] = __builtin_amdgcn_mfma_f32_16x16x32_f16(
                    af[mi], bf[ni], acc[mi][ni], 0, 0, 0);
    };
    auto epilogue = [&](int nt) {
        const int col0g = chunk * NR + nt * BN;
#pragma unroll
        for (int s = 0; s < 8; ++s) {
            if (wn == (s >> 2)) {
                const int ni = s & 3;
#pragma unroll
                for (int mi = 0; mi < 4; ++mi)
#pragma unroll
                    for (int r = 0; r < 4; ++r) {
                        const int row = wm * 64 + mi * 16 + (lane >> 4) * 4 + r;
                        Cs[row * CS_STRIDE + (lane & 15)] = acc[mi][ni][r];
                    }
            }
            asm volatile("s_waitcnt lgkmcnt(0)" ::: "memory");
            __builtin_amdgcn_s_barrier();
            {
                const int row = tid >> 1, hf = tid & 1;
                const int base = col0g + s * 16 + hf * 8;
                for (int c = 0; c < 8; ++c) {
                    const float v = Cs[row * CS_STRIDE + hf * 8 + c];
                    const int id = base + c;
                    if (v > topv[CAND - 1] ||
                        (v == topv[CAND - 1] && id < topi[CAND - 1])) {
                        topv[CAND - 1] = v; topi[CAND - 1] = id;
#pragma unroll
                        for (int t = CAND - 1; t > 0; --t) {
                            const bool gt = topv[t] > topv[t - 1] ||
                                (topv[t] == topv[t - 1] && topi[t] < topi[t - 1]);
                            if (gt) {
                                const float tv = topv[t]; topv[t] = topv[t - 1]; topv[t - 1] = tv;
                                const int   ti = topi[t]; topi[t] = topi[t - 1]; topi[t - 1] = ti;
                            }
                        }
                    }
                }
            }
            asm volatile("s_waitcnt lgkmcnt(0)" ::: "memory");
            __builtin_amdgcn_s_barrier();
        }
#pragma unroll
        for (int mi = 0; mi < 4; ++mi)
#pragma unroll
            for (int ni = 0; ni < 4; ++ni) acc[mi][ni] = (f32x4)0.0f;
    };

    // prologue: 3 steps in flight (12 glds); drain step 0's 4, keep 8.
    issue(0, 0); issue(1, 1); issue(2, 2);
    asm volatile("s_waitcnt vmcnt(8)" ::: "memory");
    __builtin_amdgcn_s_barrier();

    for (int j = 0; j < ITERS - 4; j += 4) {
#pragma unroll
        for (int u = 0; u < 4; ++u) {
            const int jj = j + u;
            issue(jj + 3, (u + 3) & 3);
            compute(u);
            asm volatile("s_waitcnt vmcnt(8) lgkmcnt(0)" ::: "memory");
            __builtin_amdgcn_s_barrier();
            if ((jj & 15) == 15) epilogue(jj >> 4);
        }
    }
    // tail: jj = 124..127 (bufs 0..3)
    issue(127, 3);
    compute(0);
    asm volatile("s_waitcnt vmcnt(8) lgkmcnt(0)" ::: "memory");
    __builtin_amdgcn_s_barrier();
    compute(1);
    asm volatile("s_waitcnt vmcnt(4) lgkmcnt(0)" ::: "memory");
    __builtin_amdgcn_s_barrier();
    compute(2);
    asm volatile("s_waitcnt vmcnt(0) lgkmcnt(0)" ::: "memory");
    __builtin_amdgcn_s_barrier();
    compute(3);
    epilogue(7);

    // merge even/odd half-row scans, emit top-6
    float ov[CAND]; int oi[CAND];
#pragma unroll
    for (int j = 0; j < CAND; ++j) {
        ov[j] = __shfl_xor(topv[j], 1);
        oi[j] = __shfl_xor(topi[j], 1);
    }
    if ((tid & 1) == 0) {
        float mv[CAND]; int mx[CAND];
        int a = 0, b = 0;
#pragma unroll
        for (int t = 0; t < CAND; ++t) {
            const bool ta = (b >= CAND) ||
                (a < CAND && (topv[a] > ov[b] ||
                              (topv[a] == ov[b] && topi[a] < oi[b])));
            mv[t] = ta ? topv[a] : ov[b];
            mx[t] = ta ? topi[a] : oi[b];
            if (ta) ++a; else ++b;
        }
        const int rowg = qt * BM + (tid >> 1);
        const size_t base = ((size_t)rowg * CHUNKS + chunk) * CAND;
#pragma unroll
        for (int t = 0; t < CAND; ++t) {
            cand_v[base + t] = mv[t];
            cand_i[base + t] = mx[t];
        }
    }
}

// --------------------------------------------------------------------- p2 --
// One block per row. Pivot = 24th-largest chunk-head under (v desc, idx asc)
// => pool {e >= pivot} provably contains the f16-top-24 => true top-10.
// Exact fp32 rescore of the pool from original Q,X; deterministic rank.
__global__ __launch_bounds__(256)
void faiss_p2(const float* __restrict__ cand_v, const int* __restrict__ cand_i,
              const float* __restrict__ Q, const float* __restrict__ X,
              int* __restrict__ out)
{
    __shared__ float vs[NCAND];
    __shared__ int   is[NCAND];
    __shared__ float qs[D_DIM];
    __shared__ int   Sidx[NCAND];
    __shared__ float Sval[NCAND];
    __shared__ int   scount;
    __shared__ float pivV;
    __shared__ int   pivI;

    const int row = blockIdx.x, tid = threadIdx.x;

    for (int i = tid; i < NCAND; i += 256) {
        vs[i] = cand_v[(size_t)row * NCAND + i];
        is[i] = cand_i[(size_t)row * NCAND + i];
    }
    if (tid < 128)
        ((float4*)qs)[tid] = ((const float4*)(Q + (size_t)row * D_DIM))[tid];
    if (tid == 0) scount = 0;
    __syncthreads();

    {
        const float h = vs[tid * CAND];
        const int  hid = is[tid * CAND];
        int r = 0;
        for (int j = 0; j < CHUNKS; ++j) {
            const float vj = vs[j * CAND];
            r += (vj > h) || (vj == h && is[j * CAND] < hid);
        }
        if (r == 23) { pivV = h; pivI = hid; }
    }
    __syncthreads();

    const float pv = pivV; const int pi = pivI;
    for (int i = tid; i < NCAND; i += 256) {
        const float v = vs[i]; const int id = is[i];
        if (v > pv || (v == pv && id <= pi)) {
            const int p = atomicAdd(&scount, 1);
            Sidx[p] = id;
        }
    }
    __syncthreads();
    const int nS = scount;

    const int wv = tid >> 6, ln = tid & 63;
    for (int si = wv; si < nS; si += 4) {
        const float* xr = X + (size_t)Sidx[si] * D_DIM + ln * 8;
        const float4 xa = *(const float4*)(xr);
        const float4 xb = *(const float4*)(xr + 4);
        const float* qp = qs + ln * 8;
        float s = 0.0f;
        s = fmaf(qp[0], xa.x, s); s = fmaf(qp[1], xa.y, s);
        s = fmaf(qp[2], xa.z, s); s = fmaf(qp[3], xa.w, s);
        s = fmaf(qp[4], xb.x, s); s = fmaf(qp[5], xb.y, s);
        s = fmaf(qp[6], xb.z, s); s = fmaf(qp[7], xb.w, s);
#pragma unroll
        for (int off = 32; off > 0; off >>= 1)
            s += __shfl_down(s, off);
        if (ln == 0) Sval[si] = s;
    }
    __syncthreads();

    for (int i = tid; i < nS; i += 256) {
        const float v = Sval[i]; const int id = Sidx[i];
        int r = 0;
        for (int j = 0; j < nS; ++j) {
            const float vj = Sval[j];
            r += (vj > v) || (vj == v && Sidx[j] < id);
        }
        if (r < TOPK) out[row * TOPK + r] = id;
    }
}

// ----------------------------------------------------------------- launch --
extern "C" void kernel_launch(void* const* d_in, const int* in_sizes, int n_in,
                              void* d_out, int out_size, void* d_ws, size_t ws_size,
                              hipStream_t stream)
{
    (void)in_sizes; (void)n_in; (void)out_size; (void)ws_size;
    const float* Q = (const float*)d_in[0];
    const float* X = (const float*)d_in[1];
    int* out = (int*)d_out;

    char* ws = (char*)d_ws;
    float* cand_v = (float*)ws;                              // 3.15 MB
    int*   cand_i = (int*)(ws + (size_t)B_Q * NCAND * 4);    // 3.15 MB
    uint4* Qsw4   = (uint4*)(ws + (size_t)B_Q * NCAND * 8);  // 512 KB
    uint4* Xt4    = (uint4*)(ws + (size_t)B_Q * NCAND * 8 + 524288);  // 268 MB

    qprep<<<dim3(128), dim3(256), 0, stream>>>(Q, Qsw4);
    xprep_tiled<<<dim3(2048), dim3(256), 0, stream>>>(X, Xt4);
    faiss_p1<<<dim3(1024), dim3(256), 0, stream>>>(Qsw4, Xt4, cand_v, cand_i);
    faiss_p2<<<dim3(B_Q), dim3(256), 0, stream>>>(cand_v, cand_i, Q, X, out);
}

// Round 11
// 624.544 us; speedup vs baseline: 5.2991x; 5.2991x over previous
//
#include <hip/hip_runtime.h>
#include <stdint.h>

// IndexFlatIP top-k: sims = Q[512,512] @ X[262144,512]^T, per-row top-10
// indices (desc, ties -> lower index). Output int32 [512,10].
//
// Round 11 = round-5 (proven 520us) with ONE change: wave tile 64x32 -> 64x64
// (BN 64->128). Steps halve (256->128), MFMA:ds_read per step doubles.
// Register budget stays under the 128-unified cliff (r5 56 + 32 acc + 8 breg
// + 8 frag ~= 112) so the 2-blocks-of-8-waves overlap regime survives.
//  qprep: Q fp32 -> f16 RTZ granules, r5-verbatim layout.
//  p1   : BM=256 BN=128 BK=32, 512 thr = 8 waves (4M x 2N). A via glds
//         (L2-resident Qsw), B reg-staged fp32->f16 (2 sets, 2-step slack),
//         vmcnt(2)/step drains exactly [B(j), A(j)], keeps B(j+1) in flight.
//         Fused per-row top-6 per 1024-col chunk (r5 epilogue, 8 slabs).
//  p2   : pivot-filter + exact fp32 rescore (verified rounds 5-10).
#define B_Q   512
#define N_IDX 262144
#define D_DIM 512
#define TOPK  10
#define CAND  6

constexpr int CHUNKS = 256;          // candidate chunks (1024 cols each)
constexpr int NR = N_IDX / CHUNKS;   // 1024
constexpr int BM = 256, BN = 128, BK = 32;
constexpr int NT = NR / BN;          // 8
constexpr int KT = D_DIM / BK;       // 16
constexpr int ITERS = NT * KT;       // 128
constexpr int NCAND = CHUNKS * CAND; // 1536

typedef _Float16 half8 __attribute__((ext_vector_type(8)));
typedef float    f32x4 __attribute__((ext_vector_type(4)));

__device__ __forceinline__ unsigned int pk16(float a, float b)
{
    return __builtin_bit_cast(unsigned int, __builtin_amdgcn_cvt_pkrtz(a, b));
}

__device__ __forceinline__ void glds16(const void* g, char* lds)
{
    __builtin_amdgcn_global_load_lds(
        (const __attribute__((address_space(1))) void*)g,
        (__attribute__((address_space(3))) void*)lds, 16, 0, 0);
}

// ------------------------------------------------------------------ qprep --
// r5-verbatim: tile (qt 0..1, kt 0..15) of 1024 granules; granule =
// slot*256 + row (slot = k-octet 0..3, row 0..255), 16 B each.
__global__ __launch_bounds__(256)
void qprep(const float* __restrict__ Q, uint4* __restrict__ Qsw4)
{
    const int n = blockIdx.x * 256 + threadIdx.x;   // 32768 granules
    const float4 p0 = reinterpret_cast<const float4*>(Q)[n * 2];
    const float4 p1 = reinterpret_cast<const float4*>(Q)[n * 2 + 1];
    uint4 u;
    u.x = pk16(p0.x, p0.y);
    u.y = pk16(p0.z, p0.w);
    u.z = pk16(p1.x, p1.y);
    u.w = pk16(p1.z, p1.w);
    const int kslot = n & 63, rowg = n >> 6;
    const int kt = kslot >> 2, slot = kslot & 3;
    const int qt = rowg >> 8, row = rowg & 255;
    Qsw4[(qt * 16 + kt) * 1024 + slot * 256 + row] = u;
}

// --------------------------------------------------------------------- p1 --
// Grid 512 (chunk = bx>>1, qt = bx&1), block 512 = 8 waves (wm 0..3, wn 0..1),
// wave tile 64x64, acc 4x4 f32x4 = 64 VGPR.
// LDS 65536: Abuf[2] 16K @0/@16K, Bbuf[2] 8K @32K/@40K, Cs 256x16 f32 @49152.
__global__ __launch_bounds__(512, 4)
void faiss_p1(const uint4* __restrict__ Qsw4, const float* __restrict__ X,
              float* __restrict__ cand_v, int* __restrict__ cand_i)
{
    __shared__ __align__(16) char smem[65536];
    float* Cs = (float*)(smem + 49152);

    const int tid  = threadIdx.x;
    const int lane = tid & 63;
    const int w    = tid >> 6;
    const int wm   = w >> 1;       // 0..3 (M quarter, 64 rows)
    const int wn   = w & 1;        // 0..1 (N half, 64 cols)
    const int chunk = blockIdx.x >> 1;
    const int qt    = blockIdx.x & 1;
    const int row0  = qt * 256;

    // A staging (r5-verbatim): wave w stages granules w*128 + {0..63,64..127}.
    const uint4* aTile = Qsw4 + qt * (16 * 1024) + w * 128 + lane;
    const int aDst = (w * 128) * 16;               // wave-uniform LDS bytes

    // B staging: thread -> (col = tid>>2, kq = tid&3): 8 f32 -> 1 granule.
    const int bcol = tid >> 2, bkq = tid & 3;
    const int bD = (bkq * 128 + bcol) * 16;        // granule kq*128+col

    // fragment LDS byte offsets (koct = lane>>4)
    int a_off[4], b_off[4];
#pragma unroll
    for (int i = 0; i < 4; ++i) {
        a_off[i] = ((lane >> 4) * 256 + wm * 64 + i * 16 + (lane & 15)) * 16;
        b_off[i] = ((lane >> 4) * 128 + wn * 64 + i * 16 + (lane & 15)) * 16;
    }

    float topv[CAND]; int topi[CAND];
#pragma unroll
    for (int j = 0; j < CAND; ++j) { topv[j] = -3.0e38f; topi[j] = 0; }

    f32x4 acc[4][4];
#pragma unroll
    for (int mi = 0; mi < 4; ++mi)
#pragma unroll
        for (int ni = 0; ni < 4; ++ni) acc[mi][ni] = (f32x4)0.0f;

    // 2 static B register sets (8 f32 each): B(k) lives in set k&1
    float4 bE[2], bO[2];

#define ISSUE_A(J)  do {                                                    \
        const uint4* _s = aTile + ((J) & 15) * 1024;                        \
        char* _d = smem + ((J) & 1) * 16384;                                \
        glds16(_s,      _d + aDst);                                         \
        glds16(_s + 64, _d + aDst + 1024);                                  \
    } while (0)

#define ISSUE_B(J, SET)  do {                                               \
        const float* _p = X + (size_t)(chunk * NR + ((J) >> 4) * BN + bcol) * D_DIM \
                            + ((J) & 15) * 32 + bkq * 8;                    \
        SET[0] = *reinterpret_cast<const float4*>(_p);                      \
        SET[1] = *reinterpret_cast<const float4*>(_p + 4);                  \
    } while (0)

#define WRITE_B(J, SET)  do {                                               \
        char* _bb = smem + 32768 + ((J) & 1) * 8192;                        \
        uint4 _u;                                                           \
        _u.x = pk16(SET[0].x, SET[0].y); _u.y = pk16(SET[0].z, SET[0].w);   \
        _u.z = pk16(SET[1].x, SET[1].y); _u.w = pk16(SET[1].z, SET[1].w);   \
        *(uint4*)(_bb + bD) = _u;                                           \
    } while (0)

#define COMPUTE(J)  do {                                                    \
        const char* _ab = smem + ((J) & 1) * 16384;                         \
        const char* _bb = smem + 32768 + ((J) & 1) * 8192;                  \
        half8 _af[4], _bf[4];                                               \
        for (int _m = 0; _m < 4; ++_m)                                      \
            _af[_m] = *reinterpret_cast<const half8*>(_ab + a_off[_m]);     \
        for (int _n = 0; _n < 4; ++_n)                                      \
            _bf[_n] = *reinterpret_cast<const half8*>(_bb + b_off[_n]);     \
        for (int _m = 0; _m < 4; ++_m)                                      \
            for (int _n = 0; _n < 4; ++_n)                                  \
                acc[_m][_n] = __builtin_amdgcn_mfma_f32_16x16x32_f16(       \
                    _af[_m], _bf[_n], acc[_m][_n], 0, 0, 0);                \
    } while (0)

    auto epilogue = [&](int nt) {
        const int colbase = chunk * NR + nt * BN;
#pragma unroll
        for (int s = 0; s < 8; ++s) {
            if (wn == (s >> 2)) {
                const int ni = s & 3;
#pragma unroll
                for (int mi = 0; mi < 4; ++mi)
#pragma unroll
                    for (int r = 0; r < 4; ++r) {
                        const int rr = wm * 64 + mi * 16 + (lane >> 4) * 4 + r;
                        Cs[rr * 16 + ((lane & 15) ^ ((rr >> 1) & 15))] = acc[mi][ni][r];
                    }
            }
            asm volatile("s_waitcnt lgkmcnt(0)" ::: "memory");
            __builtin_amdgcn_s_barrier();
            if (tid < 256) {
                const int r = tid;
                const int base = colbase + s * 16;
                for (int c = 0; c < 16; ++c) {
                    const float v = Cs[r * 16 + (c ^ ((r >> 1) & 15))];
                    const int id = base + c;
                    if (v > topv[CAND - 1] ||
                        (v == topv[CAND - 1] && id < topi[CAND - 1])) {
                        topv[CAND - 1] = v; topi[CAND - 1] = id;
#pragma unroll
                        for (int t = CAND - 1; t > 0; --t) {
                            const bool gt = topv[t] > topv[t - 1] ||
                                (topv[t] == topv[t - 1] && topi[t] < topi[t - 1]);
                            if (gt) {
                                const float tv = topv[t]; topv[t] = topv[t - 1]; topv[t - 1] = tv;
                                const int   ti = topi[t]; topi[t] = topi[t - 1]; topi[t - 1] = ti;
                            }
                        }
                    }
                }
            }
            asm volatile("s_waitcnt lgkmcnt(0)" ::: "memory");
            __builtin_amdgcn_s_barrier();
        }
#pragma unroll
        for (int mi = 0; mi < 4; ++mi)
#pragma unroll
            for (int ni = 0; ni < 4; ++ni) acc[mi][ni] = (f32x4)0.0f;
    };

    // STEP(J, SET): entering FIFO = [B(J):2, A(J):2, B(J+1):2].
    // vmcnt(2) drains B(J)+A(J), keeps B(J+1). SET = set(J&1) holds B(J),
    // freed by WRITE_B, reused by ISSUE_B(J+2).
#define STEP(J, SET)  do {                                                  \
        asm volatile("s_waitcnt vmcnt(2)" ::: "memory");                    \
        __builtin_amdgcn_sched_barrier(0);                                  \
        WRITE_B(J, SET);                                                    \
        asm volatile("s_waitcnt lgkmcnt(0)" ::: "memory");                  \
        __builtin_amdgcn_s_barrier();                                       \
        ISSUE_A((J) + 1);                                                   \
        __builtin_amdgcn_sched_barrier(0);                                  \
        ISSUE_B((J) + 2, SET);                                              \
        __builtin_amdgcn_sched_barrier(0);                                  \
        COMPUTE(J);                                                         \
        if (((J) & 15) == 15) epilogue((J) >> 4);                           \
    } while (0)

    // prologue: establish steady FIFO for step 0 (no waits, no barrier)
    ISSUE_B(0, bE);
    __builtin_amdgcn_sched_barrier(0);
    ISSUE_A(0);
    __builtin_amdgcn_sched_barrier(0);
    ISSUE_B(1, bO);
    __builtin_amdgcn_sched_barrier(0);

    // steady steps 0..125
    for (int j = 0; j < 126; j += 2) {
        STEP(j,     bE);
        STEP(j + 1, bO);
    }

    // step 126: no ISSUE_B(128). exit FIFO = [B(127):2, A(127):2]
    asm volatile("s_waitcnt vmcnt(2)" ::: "memory");
    WRITE_B(126, bE);
    asm volatile("s_waitcnt lgkmcnt(0)" ::: "memory");
    __builtin_amdgcn_s_barrier();
    ISSUE_A(127);
    __builtin_amdgcn_sched_barrier(0);
    COMPUTE(126);

    // step 127
    asm volatile("s_waitcnt vmcnt(0)" ::: "memory");
    WRITE_B(127, bO);
    asm volatile("s_waitcnt lgkmcnt(0)" ::: "memory");
    __builtin_amdgcn_s_barrier();
    COMPUTE(127);
    epilogue(7);

    if (tid < 256) {
        const size_t base = ((size_t)(row0 + tid) * CHUNKS + chunk) * CAND;
#pragma unroll
        for (int j = 0; j < CAND; ++j) {
            cand_v[base + j] = topv[j];
            cand_i[base + j] = topi[j];
        }
    }
#undef STEP
#undef COMPUTE
#undef WRITE_B
#undef ISSUE_B
#undef ISSUE_A
}

// --------------------------------------------------------------------- p2 --
// One block per row. Pivot = 24th-largest chunk-head under (v desc, idx asc)
// => pool {e >= pivot} provably contains the f16-top-24 => true top-10.
// Exact fp32 rescore of the pool from original Q,X; deterministic rank.
__global__ __launch_bounds__(256)
void faiss_p2(const float* __restrict__ cand_v, const int* __restrict__ cand_i,
              const float* __restrict__ Q, const float* __restrict__ X,
              int* __restrict__ out)
{
    __shared__ float vs[NCAND];
    __shared__ int   is[NCAND];
    __shared__ float qs[D_DIM];
    __shared__ int   Sidx[NCAND];
    __shared__ float Sval[NCAND];
    __shared__ int   scount;
    __shared__ float pivV;
    __shared__ int   pivI;

    const int row = blockIdx.x, tid = threadIdx.x;

    for (int i = tid; i < NCAND; i += 256) {
        vs[i] = cand_v[(size_t)row * NCAND + i];
        is[i] = cand_i[(size_t)row * NCAND + i];
    }
    if (tid < 128)
        ((float4*)qs)[tid] = ((const float4*)(Q + (size_t)row * D_DIM))[tid];
    if (tid == 0) scount = 0;
    __syncthreads();

    {
        const float h = vs[tid * CAND];
        const int  hid = is[tid * CAND];
        int r = 0;
        for (int j = 0; j < CHUNKS; ++j) {
            const float vj = vs[j * CAND];
            r += (vj > h) || (vj == h && is[j * CAND] < hid);
        }
        if (r == 23) { pivV = h; pivI = hid; }
    }
    __syncthreads();

    const float pv = pivV; const int pi = pivI;
    for (int i = tid; i < NCAND; i += 256) {
        const float v = vs[i]; const int id = is[i];
        if (v > pv || (v == pv && id <= pi)) {
            const int p = atomicAdd(&scount, 1);
            Sidx[p] = id;
        }
    }
    __syncthreads();
    const int nS = scount;

    const int wv = tid >> 6, ln = tid & 63;
    for (int si = wv; si < nS; si += 4) {
        const float* xr = X + (size_t)Sidx[si] * D_DIM + ln * 8;
        const float4 xa = *(const float4*)(xr);
        const float4 xb = *(const float4*)(xr + 4);
        const float* qp = qs + ln * 8;
        float s = 0.0f;
        s = fmaf(qp[0], xa.x, s); s = fmaf(qp[1], xa.y, s);
        s = fmaf(qp[2], xa.z, s); s = fmaf(qp[3], xa.w, s);
        s = fmaf(qp[4], xb.x, s); s = fmaf(qp[5], xb.y, s);
        s = fmaf(qp[6], xb.z, s); s = fmaf(qp[7], xb.w, s);
#pragma unroll
        for (int off = 32; off > 0; off >>= 1)
            s += __shfl_down(s, off);
        if (ln == 0) Sval[si] = s;
    }
    __syncthreads();

    for (int i = tid; i < nS; i += 256) {
        const float v = Sval[i]; const int id = Sidx[i];
        int r = 0;
        for (int j = 0; j < nS; ++j) {
            const float vj = Sval[j];
            r += (vj > v) || (vj == v && Sidx[j] < id);
        }
        if (r < TOPK) out[row * TOPK + r] = id;
    }
}

// ----------------------------------------------------------------- launch --
extern "C" void kernel_launch(void* const* d_in, const int* in_sizes, int n_in,
                              void* d_out, int out_size, void* d_ws, size_t ws_size,
                              hipStream_t stream)
{
    (void)in_sizes; (void)n_in; (void)out_size; (void)ws_size;
    const float* Q = (const float*)d_in[0];
    const float* X = (const float*)d_in[1];
    int* out = (int*)d_out;

    char* ws = (char*)d_ws;
    float* cand_v = (float*)ws;                              // 3.15 MB
    int*   cand_i = (int*)(ws + (size_t)B_Q * NCAND * 4);    // 3.15 MB
    uint4* Qsw4   = (uint4*)(ws + (size_t)B_Q * NCAND * 8);  // 512 KB

    qprep<<<dim3(128), dim3(256), 0, stream>>>(Q, Qsw4);
    faiss_p1<<<dim3(512), dim3(512), 0, stream>>>(Qsw4, X, cand_v, cand_i);
    faiss_p2<<<dim3(B_Q), dim3(256), 0, stream>>>(cand_v, cand_i, Q, X, out);
}

// Round 12
// 614.987 us; speedup vs baseline: 5.3814x; 1.0155x over previous
//
#include <hip/hip_runtime.h>
#include <stdint.h>

// IndexFlatIP top-k: sims = Q[512,512] @ X[262144,512]^T, per-row top-10
// indices (desc, ties -> lower index). Output int32 [512,10].
//
// Round 12 = round-11 geometry (BM=256 BN=128 BK=32, 8 waves, 64x64 wave
// tile, 128 steps) with the spill channel removed:
//  - ONE B register set (r11's two sets + 64-reg acc overflowed the 64
//    arch-VGPR budget under __launch_bounds__(512,4) -> 185 MB scratch).
//  - reordered single-slack FIFO that still crosses the barrier loaded:
//    entry [B(J):2, A(J):2] -> vmcnt(2) -> WRITE_B(J) -> ISSUE_B(J+1)
//    -> vmcnt(2) (A(J) done, B(J+1) in flight) -> lgkmcnt(0) -> s_barrier
//    -> ISSUE_A(J+1) -> COMPUTE(J).
//  - X addressed by an incrementing pointer (fewer VALU/regs).
//  qprep / epilogue scan / merge / p2: logic unchanged (verified absmax=0,
//  rounds 5..11).
#define B_Q   512
#define N_IDX 262144
#define D_DIM 512
#define TOPK  10
#define CAND  6

constexpr int CHUNKS = 256;          // candidate chunks (1024 cols each)
constexpr int NR = N_IDX / CHUNKS;   // 1024
constexpr int BM = 256, BN = 128, BK = 32;
constexpr int NT = NR / BN;          // 8
constexpr int KT = D_DIM / BK;       // 16
constexpr int ITERS = NT * KT;       // 128
constexpr int NCAND = CHUNKS * CAND; // 1536

typedef _Float16 half8 __attribute__((ext_vector_type(8)));
typedef float    f32x4 __attribute__((ext_vector_type(4)));

__device__ __forceinline__ unsigned int pk16(float a, float b)
{
    return __builtin_bit_cast(unsigned int, __builtin_amdgcn_cvt_pkrtz(a, b));
}

__device__ __forceinline__ void glds16(const void* g, char* lds)
{
    __builtin_amdgcn_global_load_lds(
        (const __attribute__((address_space(1))) void*)g,
        (__attribute__((address_space(3))) void*)lds, 16, 0, 0);
}

// ------------------------------------------------------------------ qprep --
// r5-verbatim: tile (qt 0..1, kt 0..15) of 1024 granules; granule =
// slot*256 + row (slot = k-octet 0..3, row 0..255), 16 B each.
__global__ __launch_bounds__(256)
void qprep(const float* __restrict__ Q, uint4* __restrict__ Qsw4)
{
    const int n = blockIdx.x * 256 + threadIdx.x;   // 32768 granules
    const float4 p0 = reinterpret_cast<const float4*>(Q)[n * 2];
    const float4 p1 = reinterpret_cast<const float4*>(Q)[n * 2 + 1];
    uint4 u;
    u.x = pk16(p0.x, p0.y);
    u.y = pk16(p0.z, p0.w);
    u.z = pk16(p1.x, p1.y);
    u.w = pk16(p1.z, p1.w);
    const int kslot = n & 63, rowg = n >> 6;
    const int kt = kslot >> 2, slot = kslot & 3;
    const int qt = rowg >> 8, row = rowg & 255;
    Qsw4[(qt * 16 + kt) * 1024 + slot * 256 + row] = u;
}

// --------------------------------------------------------------------- p1 --
// Grid 512 (chunk = bx>>1, qt = bx&1), block 512 = 8 waves (wm 0..3, wn 0..1),
// wave tile 64x64, acc 4x4 f32x4 = 64 unified regs (AGPR side).
// LDS 65536: Abuf[2] 16K @0/@16K, Bbuf[2] 8K @32K/@40K, Cs 256x16 f32 @49152.
__global__ __launch_bounds__(512, 4)
void faiss_p1(const uint4* __restrict__ Qsw4, const float* __restrict__ X,
              float* __restrict__ cand_v, int* __restrict__ cand_i)
{
    __shared__ __align__(16) char smem[65536];
    float* Cs = (float*)(smem + 49152);

    const int tid  = threadIdx.x;
    const int lane = tid & 63;
    const int w    = tid >> 6;
    const int wm   = w >> 1;       // 0..3 (M quarter, 64 rows)
    const int wn   = w & 1;        // 0..1 (N half, 64 cols)
    const int chunk = blockIdx.x >> 1;
    const int qt    = blockIdx.x & 1;
    const int row0  = qt * 256;

    // A staging: wave w stages granules w*128 + {0..63, 64..127} of (qt,kt).
    const uint4* aTile = Qsw4 + qt * (16 * 1024) + w * 128 + lane;
    const int aDst = (w * 128) * 16;               // wave-uniform LDS bytes

    // B staging: thread -> (col = tid>>2, kq = tid&3): 8 f32 -> 1 granule.
    // Incrementing pointer: +32 floats/step; +BN*D_DIM-512 at nt boundary.
    const int bcol = tid >> 2, bkq = tid & 3;
    const float* Xp = X + (size_t)(chunk * NR + bcol) * D_DIM + bkq * 8;
    const int bD = (bkq * 128 + bcol) * 16;        // granule kq*128+col

    // fragment LDS byte offsets (koct = lane>>4)
    int a_off[4], b_off[4];
#pragma unroll
    for (int i = 0; i < 4; ++i) {
        a_off[i] = ((lane >> 4) * 256 + wm * 64 + i * 16 + (lane & 15)) * 16;
        b_off[i] = ((lane >> 4) * 128 + wn * 64 + i * 16 + (lane & 15)) * 16;
    }

    float topv[CAND]; int topi[CAND];
#pragma unroll
    for (int j = 0; j < CAND; ++j) { topv[j] = -3.0e38f; topi[j] = 0; }

    f32x4 acc[4][4];
#pragma unroll
    for (int mi = 0; mi < 4; ++mi)
#pragma unroll
        for (int ni = 0; ni < 4; ++ni) acc[mi][ni] = (f32x4)0.0f;

    // single B register set (8 f32)
    float4 bR[2];

#define ISSUE_A(J)  do {                                                    \
        const uint4* _s = aTile + ((J) & 15) * 1024;                        \
        char* _d = smem + ((J) & 1) * 16384;                                \
        glds16(_s,      _d + aDst);                                         \
        glds16(_s + 64, _d + aDst + 1024);                                  \
    } while (0)

#define ISSUE_B()  do {                                                    \
        bR[0] = *reinterpret_cast<const float4*>(Xp);                      \
        bR[1] = *reinterpret_cast<const float4*>(Xp + 4);                  \
    } while (0)

#define ADVANCE_B(J)  do {                                                 \
        Xp += 32;                                                          \
        if (((J) & 15) == 15) Xp += (size_t)BN * D_DIM - 512;              \
    } while (0)

#define WRITE_B(J)  do {                                                   \
        char* _bb = smem + 32768 + ((J) & 1) * 8192;                       \
        uint4 _u;                                                          \
        _u.x = pk16(bR[0].x, bR[0].y); _u.y = pk16(bR[0].z, bR[0].w);      \
        _u.z = pk16(bR[1].x, bR[1].y); _u.w = pk16(bR[1].z, bR[1].w);      \
        *(uint4*)(_bb + bD) = _u;                                          \
    } while (0)

#define COMPUTE(J)  do {                                                    \
        const char* _ab = smem + ((J) & 1) * 16384;                         \
        const char* _bb = smem + 32768 + ((J) & 1) * 8192;                  \
        half8 _af[4], _bf[4];                                               \
        for (int _m = 0; _m < 4; ++_m)                                      \
            _af[_m] = *reinterpret_cast<const half8*>(_ab + a_off[_m]);     \
        for (int _n = 0; _n < 4; ++_n)                                      \
            _bf[_n] = *reinterpret_cast<const half8*>(_bb + b_off[_n]);     \
        for (int _m = 0; _m < 4; ++_m)                                      \
            for (int _n = 0; _n < 4; ++_n)                                  \
                acc[_m][_n] = __builtin_amdgcn_mfma_f32_16x16x32_f16(       \
                    _af[_m], _bf[_n], acc[_m][_n], 0, 0, 0);                \
    } while (0)

    auto epilogue = [&](int nt) {
        const int colbase = chunk * NR + nt * BN;
#pragma unroll
        for (int s = 0; s < 8; ++s) {
            if (wn == (s >> 2)) {
                const int ni = s & 3;
#pragma unroll
                for (int mi = 0; mi < 4; ++mi)
#pragma unroll
                    for (int r = 0; r < 4; ++r) {
                        const int rr = wm * 64 + mi * 16 + (lane >> 4) * 4 + r;
                        Cs[rr * 16 + ((lane & 15) ^ ((rr >> 1) & 15))] = acc[mi][ni][r];
                    }
            }
            asm volatile("s_waitcnt lgkmcnt(0)" ::: "memory");
            __builtin_amdgcn_s_barrier();
            if (tid < 256) {
                const int r = tid;
                const int base = colbase + s * 16;
                for (int c = 0; c < 16; ++c) {
                    const float v = Cs[r * 16 + (c ^ ((r >> 1) & 15))];
                    const int id = base + c;
                    if (v > topv[CAND - 1] ||
                        (v == topv[CAND - 1] && id < topi[CAND - 1])) {
                        topv[CAND - 1] = v; topi[CAND - 1] = id;
#pragma unroll
                        for (int t = CAND - 1; t > 0; --t) {
                            const bool gt = topv[t] > topv[t - 1] ||
                                (topv[t] == topv[t - 1] && topi[t] < topi[t - 1]);
                            if (gt) {
                                const float tv = topv[t]; topv[t] = topv[t - 1]; topv[t - 1] = tv;
                                const int   ti = topi[t]; topi[t] = topi[t - 1]; topi[t - 1] = ti;
                            }
                        }
                    }
                }
            }
            asm volatile("s_waitcnt lgkmcnt(0)" ::: "memory");
            __builtin_amdgcn_s_barrier();
        }
#pragma unroll
        for (int mi = 0; mi < 4; ++mi)
#pragma unroll
            for (int ni = 0; ni < 4; ++ni) acc[mi][ni] = (f32x4)0.0f;
    };

    // STEP(J): entry FIFO = [B(J):2, A(J):2].
    //   vmcnt(2)  -> B(J) in regs; WRITE_B(J); ISSUE_B(J+1) (set reused);
    //   vmcnt(2)  -> A(J) landed in LDS; B(J+1) stays in flight;
    //   lgkmcnt(0) + s_barrier (B writes visible, A drained by every wave);
    //   ISSUE_A(J+1); COMPUTE(J); [epilogue].
    // Exit FIFO = [B(J+1):2, A(J+1):2]  (invariant restored).
#define STEP(J)  do {                                                       \
        asm volatile("s_waitcnt vmcnt(2)" ::: "memory");                    \
        __builtin_amdgcn_sched_barrier(0);                                  \
        WRITE_B(J);                                                         \
        ADVANCE_B(J);                                                       \
        ISSUE_B();                                                          \
        __builtin_amdgcn_sched_barrier(0);                                  \
        asm volatile("s_waitcnt vmcnt(2) lgkmcnt(0)" ::: "memory");         \
        __builtin_amdgcn_s_barrier();                                       \
        ISSUE_A((J) + 1);                                                   \
        __builtin_amdgcn_sched_barrier(0);                                  \
        COMPUTE(J);                                                         \
        if (((J) & 15) == 15) epilogue((J) >> 4);                           \
    } while (0)

    // prologue: FIFO = [B(0):2, A(0):2]
    ISSUE_B();
    __builtin_amdgcn_sched_barrier(0);
    ISSUE_A(0);
    __builtin_amdgcn_sched_barrier(0);

    for (int j = 0; j < ITERS - 1; ++j) {
        STEP(j);
    }

    // step 127 (no B(128)/A(128)): entry FIFO = [B(127):2, A(127):2]
    asm volatile("s_waitcnt vmcnt(2)" ::: "memory");
    WRITE_B(127);
    asm volatile("s_waitcnt vmcnt(0) lgkmcnt(0)" ::: "memory");
    __builtin_amdgcn_s_barrier();
    COMPUTE(127);
    epilogue(7);

    if (tid < 256) {
        const size_t base = ((size_t)(row0 + tid) * CHUNKS + chunk) * CAND;
#pragma unroll
        for (int j = 0; j < CAND; ++j) {
            cand_v[base + j] = topv[j];
            cand_i[base + j] = topi[j];
        }
    }
#undef STEP
#undef COMPUTE
#undef WRITE_B
#undef ADVANCE_B
#undef ISSUE_B
#undef ISSUE_A
}

// --------------------------------------------------------------------- p2 --
// One block per row. Pivot = 24th-largest chunk-head under (v desc, idx asc)
// => pool {e >= pivot} provably contains the f16-top-24 => true top-10.
// Exact fp32 rescore of the pool from original Q,X; deterministic rank.
__global__ __launch_bounds__(256)
void faiss_p2(const float* __restrict__ cand_v, const int* __restrict__ cand_i,
              const float* __restrict__ Q, const float* __restrict__ X,
              int* __restrict__ out)
{
    __shared__ float vs[NCAND];
    __shared__ int   is[NCAND];
    __shared__ float qs[D_DIM];
    __shared__ int   Sidx[NCAND];
    __shared__ float Sval[NCAND];
    __shared__ int   scount;
    __shared__ float pivV;
    __shared__ int   pivI;

    const int row = blockIdx.x, tid = threadIdx.x;

    for (int i = tid; i < NCAND; i += 256) {
        vs[i] = cand_v[(size_t)row * NCAND + i];
        is[i] = cand_i[(size_t)row * NCAND + i];
    }
    if (tid < 128)
        ((float4*)qs)[tid] = ((const float4*)(Q + (size_t)row * D_DIM))[tid];
    if (tid == 0) scount = 0;
    __syncthreads();

    {
        const float h = vs[tid * CAND];
        const int  hid = is[tid * CAND];
        int r = 0;
        for (int j = 0; j < CHUNKS; ++j) {
            const float vj = vs[j * CAND];
            r += (vj > h) || (vj == h && is[j * CAND] < hid);
        }
        if (r == 23) { pivV = h; pivI = hid; }
    }
    __syncthreads();

    const float pv = pivV; const int pi = pivI;
    for (int i = tid; i < NCAND; i += 256) {
        const float v = vs[i]; const int id = is[i];
        if (v > pv || (v == pv && id <= pi)) {
            const int p = atomicAdd(&scount, 1);
            Sidx[p] = id;
        }
    }
    __syncthreads();
    const int nS = scount;

    const int wv = tid >> 6, ln = tid & 63;
    for (int si = wv; si < nS; si += 4) {
        const float* xr = X + (size_t)Sidx[si] * D_DIM + ln * 8;
        const float4 xa = *(const float4*)(xr);
        const float4 xb = *(const float4*)(xr + 4);
        const float* qp = qs + ln * 8;
        float s = 0.0f;
        s = fmaf(qp[0], xa.x, s); s = fmaf(qp[1], xa.y, s);
        s = fmaf(qp[2], xa.z, s); s = fmaf(qp[3], xa.w, s);
        s = fmaf(qp[4], xb.x, s); s = fmaf(qp[5], xb.y, s);
        s = fmaf(qp[6], xb.z, s); s = fmaf(qp[7], xb.w, s);
#pragma unroll
        for (int off = 32; off > 0; off >>= 1)
            s += __shfl_down(s, off);
        if (ln == 0) Sval[si] = s;
    }
    __syncthreads();

    for (int i = tid; i < nS; i += 256) {
        const float v = Sval[i]; const int id = Sidx[i];
        int r = 0;
        for (int j = 0; j < nS; ++j) {
            const float vj = Sval[j];
            r += (vj > v) || (vj == v && Sidx[j] < id);
        }
        if (r < TOPK) out[row * TOPK + r] = id;
    }
}

// ----------------------------------------------------------------- launch --
extern "C" void kernel_launch(void* const* d_in, const int* in_sizes, int n_in,
                              void* d_out, int out_size, void* d_ws, size_t ws_size,
                              hipStream_t stream)
{
    (void)in_sizes; (void)n_in; (void)out_size; (void)ws_size;
    const float* Q = (const float*)d_in[0];
    const float* X = (const float*)d_in[1];
    int* out = (int*)d_out;

    char* ws = (char*)d_ws;
    float* cand_v = (float*)ws;                              // 3.15 MB
    int*   cand_i = (int*)(ws + (size_t)B_Q * NCAND * 4);    // 3.15 MB
    uint4* Qsw4   = (uint4*)(ws + (size_t)B_Q * NCAND * 8);  // 512 KB

    qprep<<<dim3(128), dim3(256), 0, stream>>>(Q, Qsw4);
    faiss_p1<<<dim3(512), dim3(512), 0, stream>>>(Qsw4, X, cand_v, cand_i);
    faiss_p2<<<dim3(B_Q), dim3(256), 0, stream>>>(cand_v, cand_i, Q, X, out);
}